// Round 1
// 1097.199 us; speedup vs baseline: 1.0259x; 1.0259x over previous
//
#include <hip/hip_runtime.h>
#include <math.h>

// Problem constants (from reference)
#define BSZ 4096
#define HL  20
#define NF  128
#define DM  640      // 3*NF + EF + TF
#define DIN 512      // DM - TF
#define DH  320      // DM / NHEAD

static __device__ __forceinline__ float sigmoidf_(float x){ return 1.f/(1.f+expf(-x)); }
// bf16 truncate-with-round staging helpers (LDS footprint halving)
static __device__ __forceinline__ unsigned short f2b_(float v){
    return (unsigned short)((__float_as_uint(v) + 0x8000u) >> 16);
}
static __device__ __forceinline__ float b2f_(unsigned short u){
    return __uint_as_float(((unsigned int)u) << 16);
}

// ---------------------------------------------------------------------------
// T1: combT[jc*128+jq] = (outfn_w @ out_proj_w)[jq, jc]
// grid 640, block 128
__global__ void k_comb(const float* __restrict__ outfn_w,
                       const float* __restrict__ out_proj_w,
                       float* __restrict__ combT)
{
    int jc = blockIdx.x, jq = threadIdx.x;
    float acc = 0.f;
    for (int e = 0; e < DM; ++e)
        acc += outfn_w[jq*DM + e] * out_proj_w[e*DM + jc];
    combT[jc*NF + jq] = acc;
}

// T2: ZZ[ef*128+jq]
// grid 1280, block 128
__global__ void k_zz(const float* __restrict__ in_proj_w,
                     const float* __restrict__ combT,
                     float* __restrict__ ZZ)
{
    int ef = blockIdx.x;
    int h = ef / DM, e = ef - h*DM;
    int jq = threadIdx.x;
    const float* wv = in_proj_w + (2*DM + h*DH)*DM + e;   // + dd*DM
    const float* cb = combT + (h*DH)*NF + jq;             // + dd*NF
    float acc = 0.f;
    for (int dd = 0; dd < DH; ++dd)
        acc += wv[dd*DM] * cb[dd*NF];
    ZZ[ef*NF + jq] = acc;
}

// T3: qbias
// grid 1, block 128
__global__ void k_qbias(const float* __restrict__ outfn_b,
                        const float* __restrict__ out_proj_b,
                        const float* __restrict__ outfn_w,
                        const float* __restrict__ in_proj_b,
                        const float* __restrict__ combT,
                        float* __restrict__ qb)
{
    int jq = threadIdx.x;
    float acc = outfn_b[jq];
    for (int e = 0; e < DM; ++e)  acc += out_proj_b[e] * outfn_w[jq*DM + e];
    for (int jc = 0; jc < DM; ++jc) acc += in_proj_b[2*DM + jc] * combT[jc*NF + jq];
    qb[jq] = acc;
}

// T4: transposes
// grid 960, block 256
__global__ void k_transpose(const float* __restrict__ gih,
                            const float* __restrict__ ghh,
                            float* __restrict__ giT,
                            float* __restrict__ ghT)
{
    int i = blockIdx.x*blockDim.x + threadIdx.x;
    if (i < DIN*3*NF) {
        int d = i / (3*NF), j = i - d*(3*NF);
        giT[i] = gih[j*DIN + d];
    } else {
        int i2 = i - DIN*3*NF;
        int d = i2 / (3*NF), j = i2 - d*(3*NF);
        ghT[i2] = ghh[j*NF + d];
    }
}

// K2a: qc[j]
// grid 5, block 128
__global__ void k_qc(const float* __restrict__ time_b,
                     const float* __restrict__ in_proj_w,
                     const float* __restrict__ in_proj_b,
                     float* __restrict__ qcv)
{
    __shared__ float tsr[NF];
    int tid = threadIdx.x;
    tsr[tid] = cosf(time_b[tid]);
    __syncthreads();
    int j = blockIdx.x*128 + tid;
    const float* wr = in_proj_w + j*DM + DIN;
    float acc = in_proj_b[j];
    for (int d = 0; d < NF; ++d) acc += tsr[d]*wr[d];
    qcv[j] = acc;
}

// K2a2: cc[h]
// grid 1, block 128
__global__ void k_cc(const float* __restrict__ qcv,
                     const float* __restrict__ in_proj_b,
                     float* __restrict__ cc)
{
    int wave = threadIdx.x >> 6, lane = threadIdx.x & 63;
    float acc = 0.f;
    for (int j = lane; j < DH; j += 64)
        acc += qcv[wave*DH + j] * in_proj_b[DM + wave*DH + j];
    for (int off = 32; off > 0; off >>= 1) acc += __shfl_down(acc, off);
    if (lane == 0) cc[wave] = acc;
}

// K2b: u
// grid 20, block 64
__global__ void k_u(const float* __restrict__ qcv,
                    const float* __restrict__ in_proj_w,
                    float* __restrict__ u)
{
    int d = blockIdx.x*64 + threadIdx.x;
    int h = d / DM, dd = d - h*DM;
    const float* base = in_proj_w + (DM + h*DH)*DM + dd;
    const float* q = qcv + h*DH;
    float acc = 0.f;
    for (int j = 0; j < DH; ++j) acc += q[j]*base[j*DM];
    u[d] = acc;
}

// ---------------------------------------------------------------------------
// K3: per-batch fused build + MHA attention (collapsed form), restructured:
// wave-per-row register gathering (40 outstanding loads/wave), score dot fused
// into the gather, bf16 LDS staging for the attention-weighted sum.
// grid 4096, block 256 (4 waves, 5 rows each)
__global__ __launch_bounds__(256) void k_attn1(
    const int* __restrict__ nids, const int* __restrict__ hist_nids,
    const int* __restrict__ aidsp, const int* __restrict__ eidsp,
    const float* __restrict__ hist_ts, const int* __restrict__ dirsp,
    const float* __restrict__ node_feat, const float* __restrict__ edge_feat,
    const float* __restrict__ anony_emb,
    const float* __restrict__ time_w, const float* __restrict__ time_b,
    const float* __restrict__ u, const float* __restrict__ cc,
    float* __restrict__ wbuf, float* __restrict__ lef)
{
    int b = blockIdx.x, tid = threadIdx.x;
    int wave = tid >> 6, lane = tid & 63;
    __shared__ unsigned short zh[HL][DM];   // 25.6 KB (bf16)
    __shared__ float ul[2*DM];              // 5 KB
    __shared__ float sc[2][HL];
    __shared__ float aw[2][HL];
    __shared__ int   shn[HL], sdir[HL], said[HL], seid[HL];
    __shared__ float sts[HL];

    if (tid < HL) {
        shn[tid]  = hist_nids[b*HL+tid];
        sdir[tid] = dirsp[b*HL+tid];
        said[tid] = aidsp[b*HL+tid];
        seid[tid] = eidsp[b*HL+tid];
        sts[tid]  = hist_ts[b*HL+tid];
    }
    for (int i = tid; i < 2*DM; i += 256) ul[i] = u[i];
    float twA = time_w[lane],    tbA = time_b[lane];
    float twB = time_w[64+lane], tbB = time_b[64+lane];
    __syncthreads();

    // preload u fragments for the fused score dot: c = lane + 64*s
    float ulr0[10], ulr1[10];
    #pragma unroll
    for (int s = 0; s < 10; ++s) {
        ulr0[s] = ul[s*64 + lane];
        ulr1[s] = ul[DM + s*64 + lane];
    }

    int rnid = nids[b];
    float tlast = sts[HL-1];

    // per-row indices (rows l = wave + 4*r)
    int srcv[5], dstv[5], aidv[5], eidv[5];
    float dtv[5];
    #pragma unroll
    for (int r = 0; r < 5; ++r) {
        int l = wave + 4*r;
        int hn = shn[l], dir = sdir[l];
        srcv[r] = dir ? rnid : hn;
        dstv[r] = dir ? hn : rnid;
        aidv[r] = said[l];
        eidv[r] = eidv[r] = seid[l];
        dtv[r]  = tlast - sts[l];
    }
    // issue all gathers (independent -> stay in flight together)
    float zr[5][10];
    #pragma unroll
    for (int r = 0; r < 5; ++r) {
        zr[r][0] = node_feat[srcv[r]*NF + lane];
        zr[r][1] = node_feat[srcv[r]*NF + 64 + lane];
        zr[r][2] = node_feat[dstv[r]*NF + lane];
        zr[r][3] = node_feat[dstv[r]*NF + 64 + lane];
        zr[r][4] = anony_emb[aidv[r]*NF + lane];
        zr[r][5] = anony_emb[aidv[r]*NF + 64 + lane];
        zr[r][6] = edge_feat[eidv[r]*NF + lane];
        zr[r][7] = edge_feat[eidv[r]*NF + 64 + lane];
        zr[r][8] = cosf(dtv[r]*twA + tbA);
        zr[r][9] = cosf(dtv[r]*twB + tbB);
    }
    float c0 = cc[0], c1 = cc[1];
    // process rows: lef write / zeroing, fused score dot, bf16 LDS store
    #pragma unroll
    for (int r = 0; r < 5; ++r) {
        int l = wave + 4*r;
        if (l == HL-1) {            // wave-uniform (wave 3, r 4 only)
            #pragma unroll
            for (int s = 0; s < 8; ++s) {
                lef[b*DIN + s*64 + lane] = zr[r][s];
                zr[r][s] = 0.f;
            }
        }
        float d0 = 0.f, d1 = 0.f;
        #pragma unroll
        for (int s = 0; s < 10; ++s) {
            float v = zr[r][s];
            d0 += ulr0[s]*v;
            d1 += ulr1[s]*v;
            zh[l][s*64 + lane] = f2b_(v);
        }
        for (int off = 32; off > 0; off >>= 1) {
            d0 += __shfl_down(d0, off);
            d1 += __shfl_down(d1, off);
        }
        if (lane == 0) {
            bool msk = (shn[l] == 0) && (l != HL-1);
            sc[0][l] = msk ? -1.0e9f : (d0 + c0)*0.05590169943749474f; // 1/sqrt(320)
            sc[1][l] = msk ? -1.0e9f : (d1 + c1)*0.05590169943749474f;
        }
    }
    __syncthreads();
    if (tid < 2) {
        float mx = -3.0e38f;
        for (int m = 0; m < HL; ++m) mx = fmaxf(mx, sc[tid][m]);
        float sum = 0.f;
        for (int m = 0; m < HL; ++m) { float e = expf(sc[tid][m]-mx); aw[tid][m] = e; sum += e; }
        float inv = 1.f/sum;
        for (int m = 0; m < HL; ++m) aw[tid][m] *= inv;
    }
    __syncthreads();
    #pragma unroll
    for (int i = tid; i < 2*DM; i += 256) {
        int h = i / DM, d = i - h*DM;
        float acc = 0.f;
        #pragma unroll
        for (int m = 0; m < HL; ++m) acc += aw[h][m]*b2f_(zh[m][d]);
        wbuf[b*2*DM + i] = acc;
    }
}

// ---------------------------------------------------------------------------
// Row-block GEMM: qn = wbuf @ ZZ + qbias
__global__ __launch_bounds__(256) void k_gemm_qn(const float* __restrict__ A,
                                                 const float* __restrict__ BT,
                                                 const float* __restrict__ bias,
                                                 float* __restrict__ C)
{
    constexpr int K = 2*DM;  // 1280
    __shared__ float As[8*K];   // 40 KB
    int r0 = blockIdx.x*8, tid = threadIdx.x;
    for (int i = tid; i < 8*K; i += 256) As[i] = A[r0*K + i];
    __syncthreads();
    int j = tid & (NF-1), rh = tid >> 7;
    const float* bp = BT + j;
    const float* ap = As + rh*4*K;
    float acc0=0.f, acc1=0.f, acc2=0.f, acc3=0.f;
    for (int d = 0; d < K; ++d) {
        float bv = bp[d*NF];
        acc0 += ap[d]*bv;
        acc1 += ap[K + d]*bv;
        acc2 += ap[2*K + d]*bv;
        acc3 += ap[3*K + d]*bv;
    }
    float bsv = bias[j];
    int rb = r0 + rh*4;
    C[(rb+0)*NF + j] = acc0 + bsv;
    C[(rb+1)*NF + j] = acc1 + bsv;
    C[(rb+2)*NF + j] = acc2 + bsv;
    C[(rb+3)*NF + j] = acc3 + bsv;
}

// Row-block GEMM: gi = lef @ giT + gru_b_ih
__global__ __launch_bounds__(256) void k_gemm_gi(const float* __restrict__ A,
                                                 const float* __restrict__ BT,
                                                 const float* __restrict__ bias,
                                                 float* __restrict__ C)
{
    constexpr int K = DIN;     // 512
    constexpr int N = 3*NF;    // 384
    __shared__ float As[8*K];  // 16 KB
    int r0 = blockIdx.x*8, tid = threadIdx.x;
    for (int i = tid; i < 8*K; i += 256) As[i] = A[r0*K + i];
    __syncthreads();
    int j0 = tid, j1 = tid + 256;
    bool has1 = (j1 < N);
    float a0[8] = {0,0,0,0,0,0,0,0};
    float a1[8] = {0,0,0,0,0,0,0,0};
    for (int d = 0; d < K; ++d) {
        float b0 = BT[d*N + j0];
        float b1 = 0.f;
        if (has1) b1 = BT[d*N + j1];
        #pragma unroll
        for (int r = 0; r < 8; ++r) {
            float av = As[r*K + d];
            a0[r] += av*b0;
            a1[r] += av*b1;
        }
    }
    float bs0 = bias[j0];
    for (int r = 0; r < 8; ++r) C[(r0+r)*N + j0] = a0[r] + bs0;
    if (has1) {
        float bs1 = bias[j1];
        for (int r = 0; r < 8; ++r) C[(r0+r)*N + j1] = a1[r] + bs1;
    }
}

// ---------------------------------------------------------------------------
// K4: attention2 (collapsed) + merge + GRU.  grid 4096, block 128.
__global__ __launch_bounds__(128) void k_attn2(
    const int* __restrict__ nids, const int* __restrict__ hist_nids,
    const int* __restrict__ eidsp, const float* __restrict__ hist_ts,
    const float* __restrict__ node_feat, const float* __restrict__ edge_feat,
    const float* __restrict__ time_w, const float* __restrict__ time_b,
    const float* __restrict__ attn_wq, const float* __restrict__ attn_wk,
    const float* __restrict__ attn_wv,
    const float* __restrict__ merge_w, const float* __restrict__ merge_b,
    const float* __restrict__ qn, const float* __restrict__ gi,
    const float* __restrict__ ghT, const float* __restrict__ gru_b_hh,
    float* __restrict__ hpr_out, float* __restrict__ out)
{
    int b = blockIdx.x, tid = threadIdx.x;
    __shared__ float qns[NF], qh[NF], p[3*NF], nbar[3*NF];
    __shared__ float scl[HL], al[HL];
    __shared__ float ctx2[NF], hpl[NF], nfn[NF];
    __shared__ int   shn[HL], seid[HL];
    __shared__ float sts[HL];

    if (tid < HL) {
        shn[tid]  = hist_nids[b*HL+tid];
        seid[tid] = eidsp[b*HL+tid];
        sts[tid]  = hist_ts[b*HL+tid];
    }
    qns[tid] = qn[b*NF + tid];
    nfn[tid] = node_feat[nids[b]*NF + tid];
    __syncthreads();

    float tlast = sts[HL-1];
    // qh = qn @ attn_wq
    {
        float acc = 0.f;
        for (int d = 0; d < NF; ++d) acc += qns[d]*attn_wq[d*NF + tid];
        qh[tid] = acc;
    }
    __syncthreads();
    // p[d] = sum_j attn_wk[d,j]*qh[j]
    for (int dd = tid; dd < 3*NF; dd += NF) {
        const float4* row4 = (const float4*)(attn_wk + dd*NF);
        float acc = 0.f;
        #pragma unroll
        for (int q4 = 0; q4 < NF/4; ++q4) {
            float4 w4 = row4[q4];
            acc += w4.x*qh[4*q4] + w4.y*qh[4*q4+1] + w4.z*qh[4*q4+2] + w4.w*qh[4*q4+3];
        }
        p[dd] = acc;
    }
    __syncthreads();
    // sc[l] = (p . nb[l]) / sqrt(128), gathering nb[l] straight from global
    int wave = tid >> 6, lane = tid & 63;
    for (int l = wave; l < HL; l += 2) {
        int hn = shn[l], eid = seid[l];
        float dt = tlast - sts[l];
        float acc = 0.f;
        #pragma unroll
        for (int kk = 0; kk < 6; ++kk) {
            int d = lane + 64*kk;
            float v;
            if (d < NF)            v = node_feat[hn*NF + d];
            else if (d < 2*NF)     v = edge_feat[eid*NF + (d-NF)];
            else { int dd = d-2*NF; v = cosf(dt*time_w[dd] + time_b[dd]); }
            acc += p[d]*v;
        }
        for (int off = 32; off > 0; off >>= 1) acc += __shfl_down(acc, off);
        if (lane == 0) {
            bool msk = (hn == 0) && (l != HL-1);
            scl[l] = msk ? -1.0e9f : acc*0.08838834764831845f;  // 1/sqrt(128)
        }
    }
    __syncthreads();
    if (tid == 0) {
        float mx = -3.0e38f;
        for (int m = 0; m < HL; ++m) mx = fmaxf(mx, scl[m]);
        float sum = 0.f;
        for (int m = 0; m < HL; ++m) { float e = expf(scl[m]-mx); al[m] = e; sum += e; }
        float inv = 1.f/sum;
        for (int m = 0; m < HL; ++m) al[m] *= inv;
    }
    __syncthreads();
    // nbar = sum_l a[l]*nb[l]  (second gather pass, L2-warm)
    {
        float twj = time_w[tid], tbj = time_b[tid];
        float an = 0.f, ae = 0.f, at = 0.f;
        #pragma unroll
        for (int l = 0; l < HL; ++l) {
            float a = al[l];
            an += a*node_feat[shn[l]*NF + tid];
            ae += a*edge_feat[seid[l]*NF + tid];
            at += a*cosf((tlast - sts[l])*twj + tbj);
        }
        nbar[tid]       = an;
        nbar[tid+NF]    = ae;
        nbar[tid+2*NF]  = at;
    }
    __syncthreads();
    // ctx2 = nbar @ attn_wv
    {
        float acc = 0.f;
        for (int d = 0; d < 3*NF; ++d) acc += nbar[d]*attn_wv[d*NF + tid];
        ctx2[tid] = acc;
    }
    __syncthreads();
    // h_prev_left
    {
        float acc = merge_b[tid];
        for (int d = 0; d < NF; ++d) acc += ctx2[d]*merge_w[d*NF + tid];
        for (int d = 0; d < NF; ++d) acc += nfn[d]*merge_w[(NF+d)*NF + tid];
        hpl[tid] = tanhf(acc);
    }
    __syncthreads();
    // GRU
    float ghv[3];
    #pragma unroll
    for (int s = 0; s < 3; ++s) {
        int jj = s*NF + tid;
        float acc = gru_b_hh[jj];
        for (int d = 0; d < NF; ++d) acc += hpl[d]*ghT[d*3*NF + jj];
        ghv[s] = acc;
    }
    float gi0 = gi[b*3*NF + tid];
    float gi1 = gi[b*3*NF + NF + tid];
    float gi2 = gi[b*3*NF + 2*NF + tid];
    float r_ = sigmoidf_(gi0 + ghv[0]);
    float z_ = sigmoidf_(gi1 + ghv[1]);
    float n_ = tanhf(gi2 + r_*ghv[2]);
    float hpr = (1.f - z_)*n_ + z_*hpl[tid];
    out[BSZ*NF + b*NF + tid] = hpr;            // h_right
    hpr_out[b*NF + tid] = hpr;                 // for k_ode
    if (tid == 0) out[2*BSZ*NF + b] = tlast;   // hist_ts[:, -1]
}

// ---------------------------------------------------------------------------
// K5: batched RK4 ODE, half-row split.
// Thread (j = tid>>1, h = tid&1) holds W[j][h*64 .. h*64+63] (64 VGPRs) and
// computes a 64-wide partial dot; pair lanes (xor 1, intra-wave) combine via
// __shfl_xor. Double-buffered z-exchange -> ONE barrier per eval (the barrier
// of eval e separates eval e-1's readers of a buffer from eval e+1's writers).
// Block 256 = 4 waves handles 2 batches; grid BSZ/2 = 2048.
// __launch_bounds__(256,4): cap VGPR at 128 -> 4 waves/SIMD.
static __device__ __forceinline__ void ode_eval_pair(
    float y0, float y1,            // this thread's element j of input vec, per batch
    const float4* __restrict__ wr, // 16 float4 = W[j][h*64 .. h*64+63]
    float ob, float rat0, float rat1,
    float* __restrict__ zrow,      // buffer base: [2][NF] (batch-major)
    int j, int h, float* k0, float* k1)
{
    // pair threads hold identical y values; split the two stores across h
    if (h == 0) zrow[j]      = y0;
    else        zrow[NF + j] = y1;
    __syncthreads();
    const float4* zA = (const float4*)(zrow + h*64);        // batch 0, my half
    const float4* zB = (const float4*)(zrow + NF + h*64);   // batch 1, my half
    float a0 = 0.f, b0 = 0.f, a1 = 0.f, b1 = 0.f;           // 4 acc chains (ILP)
    #pragma unroll
    for (int q = 0; q < 16; q += 2) {
        float4 w0 = wr[q],  w1 = wr[q+1];
        float4 xA0 = zA[q], xA1 = zA[q+1];
        float4 xB0 = zB[q], xB1 = zB[q+1];
        a0 += w0.x*xA0.x + w0.y*xA0.y + w0.z*xA0.z + w0.w*xA0.w;
        b0 += w1.x*xA1.x + w1.y*xA1.y + w1.z*xA1.z + w1.w*xA1.w;
        a1 += w0.x*xB0.x + w0.y*xB0.y + w0.z*xB0.z + w0.w*xB0.w;
        b1 += w1.x*xB1.x + w1.y*xB1.y + w1.z*xB1.z + w1.w*xB1.w;
    }
    float s0 = a0 + b0, s1 = a1 + b1;
    s0 += __shfl_xor(s0, 1);       // combine half-dots within the pair
    s1 += __shfl_xor(s1, 1);
    *k0 = tanhf(s0 + ob)*rat0;
    *k1 = tanhf(s1 + ob)*rat1;
}

__global__ __launch_bounds__(256, 4) void k_ode(
    const float* __restrict__ hpr, const float* __restrict__ hist_ts,
    const float* __restrict__ ode_w, const float* __restrict__ ode_b,
    const float* __restrict__ tnode_w, const float* __restrict__ tnode_b,
    float* __restrict__ out)
{
    __shared__ float zb[2][2][NF];   // [buf][batch][j], 2 KB
    int tid = threadIdx.x;
    int j = tid >> 1, h = tid & 1;
    int b0 = blockIdx.x*2;

    float4 wr[16];
    const float4* wp = (const float4*)(ode_w + j*NF + h*64);
    #pragma unroll
    for (int i = 0; i < 16; ++i) wr[i] = wp[i];
    float twj = tnode_w[j], tbj = tnode_b[j], obj = ode_b[j];

    float z0, z1, t00, t01, rat0, rat1;
    {
        float t1a = hist_ts[(b0+0)*HL + (HL-1)];
        float t1b = hist_ts[(b0+1)*HL + (HL-1)];
        t00 = hist_ts[(b0+0)*HL + (HL-2)];
        t01 = hist_ts[(b0+1)*HL + (HL-2)];
        rat0 = t1a - t00; rat1 = t1b - t01;
        z0 = hpr[(b0+0)*NF + j];
        z1 = hpr[(b0+1)*NF + j];
    }

    // teA of step s+1 == teC of step s (s-grid exact in fp32) -> 4 cos/step
    float teA0 = cosf(t00*twj + tbj);
    float teA1 = cosf(t01*twj + tbj);
    #pragma unroll 1
    for (int stp = 0; stp < 8; ++stp) {
        float s0 = stp*0.125f;
        float teB0 = cosf(((s0 + 0.0625f)*rat0 + t00)*twj + tbj);
        float teB1 = cosf(((s0 + 0.0625f)*rat1 + t01)*twj + tbj);
        float teC0 = cosf(((s0 + 0.125f)*rat0 + t00)*twj + tbj);
        float teC1 = cosf(((s0 + 0.125f)*rat1 + t01)*twj + tbj);
        float k10, k11, k20, k21, k30, k31, k40, k41;
        ode_eval_pair(z0 + teA0,               z1 + teA1,               wr, obj, rat0, rat1, &zb[0][0][0], j, h, &k10, &k11);
        ode_eval_pair(z0 + 0.0625f*k10 + teB0, z1 + 0.0625f*k11 + teB1, wr, obj, rat0, rat1, &zb[1][0][0], j, h, &k20, &k21);
        ode_eval_pair(z0 + 0.0625f*k20 + teB0, z1 + 0.0625f*k21 + teB1, wr, obj, rat0, rat1, &zb[0][0][0], j, h, &k30, &k31);
        ode_eval_pair(z0 + 0.125f*k30 + teC0,  z1 + 0.125f*k31 + teC1,  wr, obj, rat0, rat1, &zb[1][0][0], j, h, &k40, &k41);
        z0 += (0.125f/6.f)*(k10 + 2.f*k20 + 2.f*k30 + k40);
        z1 += (0.125f/6.f)*(k11 + 2.f*k21 + 2.f*k31 + k41);
        teA0 = teC0; teA1 = teC1;
    }
    if (h == 0) {
        out[(b0+0)*NF + j] = z0;   // h_left
        out[(b0+1)*NF + j] = z1;
    }
}

// ---------------------------------------------------------------------------
extern "C" void kernel_launch(void* const* d_in, const int* in_sizes, int n_in,
                              void* d_out, int out_size, void* d_ws, size_t ws_size,
                              hipStream_t stream)
{
    (void)in_sizes; (void)n_in; (void)out_size; (void)ws_size;
    const int*   nids      = (const int*)d_in[0];
    const int*   hist_nids = (const int*)d_in[2];
    const int*   aids      = (const int*)d_in[3];
    const int*   eids      = (const int*)d_in[4];
    const float* hist_ts   = (const float*)d_in[5];
    const int*   dirs      = (const int*)d_in[6];
    const float* node_feat = (const float*)d_in[7];
    const float* edge_feat = (const float*)d_in[8];
    const float* anony_emb = (const float*)d_in[9];
    const float* time_w    = (const float*)d_in[10];
    const float* time_b    = (const float*)d_in[11];
    const float* in_proj_w = (const float*)d_in[12];
    const float* in_proj_b = (const float*)d_in[13];
    const float* out_proj_w= (const float*)d_in[14];
    const float* out_proj_b= (const float*)d_in[15];
    const float* outfn_w   = (const float*)d_in[16];
    const float* outfn_b   = (const float*)d_in[17];
    const float* attn_wq   = (const float*)d_in[18];
    const float* attn_wk   = (const float*)d_in[19];
    const float* attn_wv   = (const float*)d_in[20];
    const float* merge_w   = (const float*)d_in[21];
    const float* merge_b   = (const float*)d_in[22];
    const float* gru_w_ih  = (const float*)d_in[23];
    const float* gru_w_hh  = (const float*)d_in[24];
    const float* gru_b_ih  = (const float*)d_in[25];
    const float* gru_b_hh  = (const float*)d_in[26];
    const float* ode_w     = (const float*)d_in[27];
    const float* ode_b     = (const float*)d_in[28];
    const float* tnode_w   = (const float*)d_in[29];
    const float* tnode_b   = (const float*)d_in[30];
    float* out = (float*)d_out;

    float* ws    = (float*)d_ws;
    float* qc    = ws;                   // 640
    float* cc    = ws + 640;             // 2
    float* u     = ws + 768;             // 1280
    float* wbuf  = ws + 2048;            // 4096*1280
    float* lef   = wbuf + BSZ*2*DM;      // 4096*512
    float* qn    = lef + BSZ*DIN;        // 4096*128
    float* gi    = qn + BSZ*NF;          // 4096*384
    float* combT = gi + BSZ*3*NF;        // 640*128
    float* ZZ    = combT + DM*NF;        // 1280*128
    float* qb    = ZZ + 2*DM*NF;         // 128
    float* giT   = qb + NF;              // 512*384
    float* ghT   = giT + DIN*3*NF;       // 128*384
    // hpr aliases wbuf: wbuf's last reader (k_gemm_qn) precedes k_attn2 on
    // the same stream, so reuse is safe.
    float* hpr   = wbuf;                 // 4096*128

    // per-launch constant precomputes
    k_comb<<<DM, NF, 0, stream>>>(outfn_w, out_proj_w, combT);
    k_zz<<<2*DM, NF, 0, stream>>>(in_proj_w, combT, ZZ);
    k_qbias<<<1, NF, 0, stream>>>(outfn_b, out_proj_b, outfn_w, in_proj_b, combT, qb);
    k_transpose<<<960, 256, 0, stream>>>(gru_w_ih, gru_w_hh, giT, ghT);
    k_qc<<<5, 128, 0, stream>>>(time_b, in_proj_w, in_proj_b, qc);
    k_cc<<<1, 128, 0, stream>>>(qc, in_proj_b, cc);
    k_u<<<HL, 64, 0, stream>>>(qc, in_proj_w, u);

    // main pipeline
    k_attn1<<<BSZ, 256, 0, stream>>>(nids, hist_nids, aids, eids, hist_ts, dirs,
                                     node_feat, edge_feat, anony_emb,
                                     time_w, time_b, u, cc, wbuf, lef);
    k_gemm_qn<<<BSZ/8, 256, 0, stream>>>(wbuf, ZZ, qb, qn);
    k_gemm_gi<<<BSZ/8, 256, 0, stream>>>(lef, giT, gru_b_ih, gi);
    k_attn2<<<BSZ, 128, 0, stream>>>(nids, hist_nids, eids, hist_ts,
                                     node_feat, edge_feat, time_w, time_b,
                                     attn_wq, attn_wk, attn_wv, merge_w, merge_b,
                                     qn, gi, ghT, gru_b_hh, hpr, out);
    k_ode<<<BSZ/2, 256, 0, stream>>>(hpr, hist_ts, ode_w, ode_b,
                                     tnode_w, tnode_b, out);
}

// Round 2
// 1006.252 us; speedup vs baseline: 1.1186x; 1.0904x over previous
//
#include <hip/hip_runtime.h>
#include <math.h>

// Problem constants (from reference)
#define BSZ 4096
#define HL  20
#define NF  128
#define DM  640      // 3*NF + EF + TF
#define DIN 512      // DM - TF
#define DH  320      // DM / NHEAD

static __device__ __forceinline__ float sigmoidf_(float x){ return 1.f/(1.f+expf(-x)); }
// bf16 truncate-with-round staging helpers (LDS footprint halving)
static __device__ __forceinline__ unsigned short f2b_(float v){
    return (unsigned short)((__float_as_uint(v) + 0x8000u) >> 16);
}
static __device__ __forceinline__ float b2f_(unsigned short u){
    return __uint_as_float(((unsigned int)u) << 16);
}

// ---------------------------------------------------------------------------
// T1: combT[jc*128+jq] = (outfn_w @ out_proj_w)[jq, jc]
// grid 640, block 128
__global__ void k_comb(const float* __restrict__ outfn_w,
                       const float* __restrict__ out_proj_w,
                       float* __restrict__ combT)
{
    int jc = blockIdx.x, jq = threadIdx.x;
    float acc = 0.f;
    for (int e = 0; e < DM; ++e)
        acc += outfn_w[jq*DM + e] * out_proj_w[e*DM + jc];
    combT[jc*NF + jq] = acc;
}

// T2: ZZ[ef*128+jq]
// grid 1280, block 128
__global__ void k_zz(const float* __restrict__ in_proj_w,
                     const float* __restrict__ combT,
                     float* __restrict__ ZZ)
{
    int ef = blockIdx.x;
    int h = ef / DM, e = ef - h*DM;
    int jq = threadIdx.x;
    const float* wv = in_proj_w + (2*DM + h*DH)*DM + e;   // + dd*DM
    const float* cb = combT + (h*DH)*NF + jq;             // + dd*NF
    float acc = 0.f;
    for (int dd = 0; dd < DH; ++dd)
        acc += wv[dd*DM] * cb[dd*NF];
    ZZ[ef*NF + jq] = acc;
}

// T3: qbias
// grid 1, block 128
__global__ void k_qbias(const float* __restrict__ outfn_b,
                        const float* __restrict__ out_proj_b,
                        const float* __restrict__ outfn_w,
                        const float* __restrict__ in_proj_b,
                        const float* __restrict__ combT,
                        float* __restrict__ qb)
{
    int jq = threadIdx.x;
    float acc = outfn_b[jq];
    for (int e = 0; e < DM; ++e)  acc += out_proj_b[e] * outfn_w[jq*DM + e];
    for (int jc = 0; jc < DM; ++jc) acc += in_proj_b[2*DM + jc] * combT[jc*NF + jq];
    qb[jq] = acc;
}

// T4: transposes
// grid 960, block 256
__global__ void k_transpose(const float* __restrict__ gih,
                            const float* __restrict__ ghh,
                            float* __restrict__ giT,
                            float* __restrict__ ghT)
{
    int i = blockIdx.x*blockDim.x + threadIdx.x;
    if (i < DIN*3*NF) {
        int d = i / (3*NF), j = i - d*(3*NF);
        giT[i] = gih[j*DIN + d];
    } else {
        int i2 = i - DIN*3*NF;
        int d = i2 / (3*NF), j = i2 - d*(3*NF);
        ghT[i2] = ghh[j*NF + d];
    }
}

// K2a: qc[j]
// grid 5, block 128
__global__ void k_qc(const float* __restrict__ time_b,
                     const float* __restrict__ in_proj_w,
                     const float* __restrict__ in_proj_b,
                     float* __restrict__ qcv)
{
    __shared__ float tsr[NF];
    int tid = threadIdx.x;
    tsr[tid] = cosf(time_b[tid]);
    __syncthreads();
    int j = blockIdx.x*128 + tid;
    const float* wr = in_proj_w + j*DM + DIN;
    float acc = in_proj_b[j];
    for (int d = 0; d < NF; ++d) acc += tsr[d]*wr[d];
    qcv[j] = acc;
}

// K2a2: cc[h]
// grid 1, block 128
__global__ void k_cc(const float* __restrict__ qcv,
                     const float* __restrict__ in_proj_b,
                     float* __restrict__ cc)
{
    int wave = threadIdx.x >> 6, lane = threadIdx.x & 63;
    float acc = 0.f;
    for (int j = lane; j < DH; j += 64)
        acc += qcv[wave*DH + j] * in_proj_b[DM + wave*DH + j];
    for (int off = 32; off > 0; off >>= 1) acc += __shfl_down(acc, off);
    if (lane == 0) cc[wave] = acc;
}

// K2b: u
// grid 20, block 64
__global__ void k_u(const float* __restrict__ qcv,
                    const float* __restrict__ in_proj_w,
                    float* __restrict__ u)
{
    int d = blockIdx.x*64 + threadIdx.x;
    int h = d / DM, dd = d - h*DM;
    const float* base = in_proj_w + (DM + h*DH)*DM + dd;
    const float* q = qcv + h*DH;
    float acc = 0.f;
    for (int j = 0; j < DH; ++j) acc += q[j]*base[j*DM];
    u[d] = acc;
}

// ---------------------------------------------------------------------------
// K3: per-batch fused build + MHA attention (collapsed form), restructured:
// wave-per-row register gathering (40 outstanding loads/wave), score dot fused
// into the gather, bf16 LDS staging for the attention-weighted sum.
// grid 4096, block 256 (4 waves, 5 rows each)
__global__ __launch_bounds__(256) void k_attn1(
    const int* __restrict__ nids, const int* __restrict__ hist_nids,
    const int* __restrict__ aidsp, const int* __restrict__ eidsp,
    const float* __restrict__ hist_ts, const int* __restrict__ dirsp,
    const float* __restrict__ node_feat, const float* __restrict__ edge_feat,
    const float* __restrict__ anony_emb,
    const float* __restrict__ time_w, const float* __restrict__ time_b,
    const float* __restrict__ u, const float* __restrict__ cc,
    float* __restrict__ wbuf, float* __restrict__ lef)
{
    int b = blockIdx.x, tid = threadIdx.x;
    int wave = tid >> 6, lane = tid & 63;
    __shared__ unsigned short zh[HL][DM];   // 25.6 KB (bf16)
    __shared__ float ul[2*DM];              // 5 KB
    __shared__ float sc[2][HL];
    __shared__ float aw[2][HL];
    __shared__ int   shn[HL], sdir[HL], said[HL], seid[HL];
    __shared__ float sts[HL];

    if (tid < HL) {
        shn[tid]  = hist_nids[b*HL+tid];
        sdir[tid] = dirsp[b*HL+tid];
        said[tid] = aidsp[b*HL+tid];
        seid[tid] = eidsp[b*HL+tid];
        sts[tid]  = hist_ts[b*HL+tid];
    }
    for (int i = tid; i < 2*DM; i += 256) ul[i] = u[i];
    float twA = time_w[lane],    tbA = time_b[lane];
    float twB = time_w[64+lane], tbB = time_b[64+lane];
    __syncthreads();

    // preload u fragments for the fused score dot: c = lane + 64*s
    float ulr0[10], ulr1[10];
    #pragma unroll
    for (int s = 0; s < 10; ++s) {
        ulr0[s] = ul[s*64 + lane];
        ulr1[s] = ul[DM + s*64 + lane];
    }

    int rnid = nids[b];
    float tlast = sts[HL-1];

    // per-row indices (rows l = wave + 4*r)
    int srcv[5], dstv[5], aidv[5], eidv[5];
    float dtv[5];
    #pragma unroll
    for (int r = 0; r < 5; ++r) {
        int l = wave + 4*r;
        int hn = shn[l], dir = sdir[l];
        srcv[r] = dir ? rnid : hn;
        dstv[r] = dir ? hn : rnid;
        aidv[r] = said[l];
        eidv[r] = eidv[r] = seid[l];
        dtv[r]  = tlast - sts[l];
    }
    // issue all gathers (independent -> stay in flight together)
    float zr[5][10];
    #pragma unroll
    for (int r = 0; r < 5; ++r) {
        zr[r][0] = node_feat[srcv[r]*NF + lane];
        zr[r][1] = node_feat[srcv[r]*NF + 64 + lane];
        zr[r][2] = node_feat[dstv[r]*NF + lane];
        zr[r][3] = node_feat[dstv[r]*NF + 64 + lane];
        zr[r][4] = anony_emb[aidv[r]*NF + lane];
        zr[r][5] = anony_emb[aidv[r]*NF + 64 + lane];
        zr[r][6] = edge_feat[eidv[r]*NF + lane];
        zr[r][7] = edge_feat[eidv[r]*NF + 64 + lane];
        zr[r][8] = cosf(dtv[r]*twA + tbA);
        zr[r][9] = cosf(dtv[r]*twB + tbB);
    }
    float c0 = cc[0], c1 = cc[1];
    // process rows: lef write / zeroing, fused score dot, bf16 LDS store
    #pragma unroll
    for (int r = 0; r < 5; ++r) {
        int l = wave + 4*r;
        if (l == HL-1) {            // wave-uniform (wave 3, r 4 only)
            #pragma unroll
            for (int s = 0; s < 8; ++s) {
                lef[b*DIN + s*64 + lane] = zr[r][s];
                zr[r][s] = 0.f;
            }
        }
        float d0 = 0.f, d1 = 0.f;
        #pragma unroll
        for (int s = 0; s < 10; ++s) {
            float v = zr[r][s];
            d0 += ulr0[s]*v;
            d1 += ulr1[s]*v;
            zh[l][s*64 + lane] = f2b_(v);
        }
        for (int off = 32; off > 0; off >>= 1) {
            d0 += __shfl_down(d0, off);
            d1 += __shfl_down(d1, off);
        }
        if (lane == 0) {
            bool msk = (shn[l] == 0) && (l != HL-1);
            sc[0][l] = msk ? -1.0e9f : (d0 + c0)*0.05590169943749474f; // 1/sqrt(320)
            sc[1][l] = msk ? -1.0e9f : (d1 + c1)*0.05590169943749474f;
        }
    }
    __syncthreads();
    if (tid < 2) {
        float mx = -3.0e38f;
        for (int m = 0; m < HL; ++m) mx = fmaxf(mx, sc[tid][m]);
        float sum = 0.f;
        for (int m = 0; m < HL; ++m) { float e = expf(sc[tid][m]-mx); aw[tid][m] = e; sum += e; }
        float inv = 1.f/sum;
        for (int m = 0; m < HL; ++m) aw[tid][m] *= inv;
    }
    __syncthreads();
    #pragma unroll
    for (int i = tid; i < 2*DM; i += 256) {
        int h = i / DM, d = i - h*DM;
        float acc = 0.f;
        #pragma unroll
        for (int m = 0; m < HL; ++m) acc += aw[h][m]*b2f_(zh[m][d]);
        wbuf[b*2*DM + i] = acc;
    }
}

// ---------------------------------------------------------------------------
// Row-block GEMM: qn = wbuf @ ZZ + qbias
__global__ __launch_bounds__(256) void k_gemm_qn(const float* __restrict__ A,
                                                 const float* __restrict__ BT,
                                                 const float* __restrict__ bias,
                                                 float* __restrict__ C)
{
    constexpr int K = 2*DM;  // 1280
    __shared__ float As[8*K];   // 40 KB
    int r0 = blockIdx.x*8, tid = threadIdx.x;
    for (int i = tid; i < 8*K; i += 256) As[i] = A[r0*K + i];
    __syncthreads();
    int j = tid & (NF-1), rh = tid >> 7;
    const float* bp = BT + j;
    const float* ap = As + rh*4*K;
    float acc0=0.f, acc1=0.f, acc2=0.f, acc3=0.f;
    for (int d = 0; d < K; ++d) {
        float bv = bp[d*NF];
        acc0 += ap[d]*bv;
        acc1 += ap[K + d]*bv;
        acc2 += ap[2*K + d]*bv;
        acc3 += ap[3*K + d]*bv;
    }
    float bsv = bias[j];
    int rb = r0 + rh*4;
    C[(rb+0)*NF + j] = acc0 + bsv;
    C[(rb+1)*NF + j] = acc1 + bsv;
    C[(rb+2)*NF + j] = acc2 + bsv;
    C[(rb+3)*NF + j] = acc3 + bsv;
}

// Row-block GEMM: gi = lef @ giT + gru_b_ih
__global__ __launch_bounds__(256) void k_gemm_gi(const float* __restrict__ A,
                                                 const float* __restrict__ BT,
                                                 const float* __restrict__ bias,
                                                 float* __restrict__ C)
{
    constexpr int K = DIN;     // 512
    constexpr int N = 3*NF;    // 384
    __shared__ float As[8*K];  // 16 KB
    int r0 = blockIdx.x*8, tid = threadIdx.x;
    for (int i = tid; i < 8*K; i += 256) As[i] = A[r0*K + i];
    __syncthreads();
    int j0 = tid, j1 = tid + 256;
    bool has1 = (j1 < N);
    float a0[8] = {0,0,0,0,0,0,0,0};
    float a1[8] = {0,0,0,0,0,0,0,0};
    for (int d = 0; d < K; ++d) {
        float b0 = BT[d*N + j0];
        float b1 = 0.f;
        if (has1) b1 = BT[d*N + j1];
        #pragma unroll
        for (int r = 0; r < 8; ++r) {
            float av = As[r*K + d];
            a0[r] += av*b0;
            a1[r] += av*b1;
        }
    }
    float bs0 = bias[j0];
    for (int r = 0; r < 8; ++r) C[(r0+r)*N + j0] = a0[r] + bs0;
    if (has1) {
        float bs1 = bias[j1];
        for (int r = 0; r < 8; ++r) C[(r0+r)*N + j1] = a1[r] + bs1;
    }
}

// ---------------------------------------------------------------------------
// K4: attention2 (collapsed) + merge + GRU.  grid 4096, block 128.
__global__ __launch_bounds__(128) void k_attn2(
    const int* __restrict__ nids, const int* __restrict__ hist_nids,
    const int* __restrict__ eidsp, const float* __restrict__ hist_ts,
    const float* __restrict__ node_feat, const float* __restrict__ edge_feat,
    const float* __restrict__ time_w, const float* __restrict__ time_b,
    const float* __restrict__ attn_wq, const float* __restrict__ attn_wk,
    const float* __restrict__ attn_wv,
    const float* __restrict__ merge_w, const float* __restrict__ merge_b,
    const float* __restrict__ qn, const float* __restrict__ gi,
    const float* __restrict__ ghT, const float* __restrict__ gru_b_hh,
    float* __restrict__ hpr_out, float* __restrict__ out)
{
    int b = blockIdx.x, tid = threadIdx.x;
    __shared__ float qns[NF], qh[NF], p[3*NF], nbar[3*NF];
    __shared__ float scl[HL], al[HL];
    __shared__ float ctx2[NF], hpl[NF], nfn[NF];
    __shared__ int   shn[HL], seid[HL];
    __shared__ float sts[HL];

    if (tid < HL) {
        shn[tid]  = hist_nids[b*HL+tid];
        seid[tid] = eidsp[b*HL+tid];
        sts[tid]  = hist_ts[b*HL+tid];
    }
    qns[tid] = qn[b*NF + tid];
    nfn[tid] = node_feat[nids[b]*NF + tid];
    __syncthreads();

    float tlast = sts[HL-1];
    // qh = qn @ attn_wq
    {
        float acc = 0.f;
        for (int d = 0; d < NF; ++d) acc += qns[d]*attn_wq[d*NF + tid];
        qh[tid] = acc;
    }
    __syncthreads();
    // p[d] = sum_j attn_wk[d,j]*qh[j]
    for (int dd = tid; dd < 3*NF; dd += NF) {
        const float4* row4 = (const float4*)(attn_wk + dd*NF);
        float acc = 0.f;
        #pragma unroll
        for (int q4 = 0; q4 < NF/4; ++q4) {
            float4 w4 = row4[q4];
            acc += w4.x*qh[4*q4] + w4.y*qh[4*q4+1] + w4.z*qh[4*q4+2] + w4.w*qh[4*q4+3];
        }
        p[dd] = acc;
    }
    __syncthreads();
    // sc[l] = (p . nb[l]) / sqrt(128), gathering nb[l] straight from global
    int wave = tid >> 6, lane = tid & 63;
    for (int l = wave; l < HL; l += 2) {
        int hn = shn[l], eid = seid[l];
        float dt = tlast - sts[l];
        float acc = 0.f;
        #pragma unroll
        for (int kk = 0; kk < 6; ++kk) {
            int d = lane + 64*kk;
            float v;
            if (d < NF)            v = node_feat[hn*NF + d];
            else if (d < 2*NF)     v = edge_feat[eid*NF + (d-NF)];
            else { int dd = d-2*NF; v = cosf(dt*time_w[dd] + time_b[dd]); }
            acc += p[d]*v;
        }
        for (int off = 32; off > 0; off >>= 1) acc += __shfl_down(acc, off);
        if (lane == 0) {
            bool msk = (hn == 0) && (l != HL-1);
            scl[l] = msk ? -1.0e9f : acc*0.08838834764831845f;  // 1/sqrt(128)
        }
    }
    __syncthreads();
    if (tid == 0) {
        float mx = -3.0e38f;
        for (int m = 0; m < HL; ++m) mx = fmaxf(mx, scl[m]);
        float sum = 0.f;
        for (int m = 0; m < HL; ++m) { float e = expf(scl[m]-mx); al[m] = e; sum += e; }
        float inv = 1.f/sum;
        for (int m = 0; m < HL; ++m) al[m] *= inv;
    }
    __syncthreads();
    // nbar = sum_l a[l]*nb[l]  (second gather pass, L2-warm)
    {
        float twj = time_w[tid], tbj = time_b[tid];
        float an = 0.f, ae = 0.f, at = 0.f;
        #pragma unroll
        for (int l = 0; l < HL; ++l) {
            float a = al[l];
            an += a*node_feat[shn[l]*NF + tid];
            ae += a*edge_feat[seid[l]*NF + tid];
            at += a*cosf((tlast - sts[l])*twj + tbj);
        }
        nbar[tid]       = an;
        nbar[tid+NF]    = ae;
        nbar[tid+2*NF]  = at;
    }
    __syncthreads();
    // ctx2 = nbar @ attn_wv
    {
        float acc = 0.f;
        for (int d = 0; d < 3*NF; ++d) acc += nbar[d]*attn_wv[d*NF + tid];
        ctx2[tid] = acc;
    }
    __syncthreads();
    // h_prev_left
    {
        float acc = merge_b[tid];
        for (int d = 0; d < NF; ++d) acc += ctx2[d]*merge_w[d*NF + tid];
        for (int d = 0; d < NF; ++d) acc += nfn[d]*merge_w[(NF+d)*NF + tid];
        hpl[tid] = tanhf(acc);
    }
    __syncthreads();
    // GRU
    float ghv[3];
    #pragma unroll
    for (int s = 0; s < 3; ++s) {
        int jj = s*NF + tid;
        float acc = gru_b_hh[jj];
        for (int d = 0; d < NF; ++d) acc += hpl[d]*ghT[d*3*NF + jj];
        ghv[s] = acc;
    }
    float gi0 = gi[b*3*NF + tid];
    float gi1 = gi[b*3*NF + NF + tid];
    float gi2 = gi[b*3*NF + 2*NF + tid];
    float r_ = sigmoidf_(gi0 + ghv[0]);
    float z_ = sigmoidf_(gi1 + ghv[1]);
    float n_ = tanhf(gi2 + r_*ghv[2]);
    float hpr = (1.f - z_)*n_ + z_*hpl[tid];
    out[BSZ*NF + b*NF + tid] = hpr;            // h_right
    hpr_out[b*NF + tid] = hpr;                 // for k_ode
    if (tid == 0) out[2*BSZ*NF + b] = tlast;   // hist_ts[:, -1]
}

// ---------------------------------------------------------------------------
// K5: batched RK4 ODE, half-row split.
// Thread (j = tid>>1, h = tid&1) holds W[j][h*64 .. h*64+63] (64 VGPRs) and
// computes a 64-wide partial dot; pair lanes (xor 1, intra-wave) combine via
// __shfl_xor. Double-buffered z-exchange -> ONE barrier per eval.
// z stored as [batch][h*68 + i] (4-float pad between halves) so the two
// broadcast addresses in each ds_read_b128 hit DISJOINT bank groups
// (64 floats = 256 B == 0 mod 32 banks would alias; 68 shifts by 4 banks).
// Block 256 = 4 waves handles 2 batches; grid BSZ/2 = 2048.
// NOTE: no min-waves hint — __launch_bounds__(256,4) previously forced
// VGPR=64 and spilled wr[] to scratch (WRITE_SIZE 2->53 MB).
#define ZPITCH 68          // floats per half (64 data + 4 pad)
#define BPITCH (2*ZPITCH)  // floats per batch row (136)

static __device__ __forceinline__ void ode_eval_pair(
    float y0, float y1,            // this thread's element j of input vec, per batch
    const float4* __restrict__ wr, // 16 float4 = W[j][h*64 .. h*64+63]
    float ob, float rat0, float rat1,
    float* __restrict__ zrow,      // buffer base: [2][BPITCH] (batch-major)
    int j, int h, float* k0, float* k1)
{
    // pair threads hold identical y values; split the two stores across h
    int wslot = (j >> 6)*ZPITCH + (j & 63);
    if (h == 0) zrow[wslot]          = y0;
    else        zrow[BPITCH + wslot] = y1;
    __syncthreads();
    const float4* zA = (const float4*)(zrow + h*ZPITCH);            // batch 0, my half
    const float4* zB = (const float4*)(zrow + BPITCH + h*ZPITCH);   // batch 1, my half
    float a0 = 0.f, b0 = 0.f, a1 = 0.f, b1 = 0.f;                   // 4 acc chains (ILP)
    #pragma unroll
    for (int q = 0; q < 16; q += 2) {
        float4 w0 = wr[q],  w1 = wr[q+1];
        float4 xA0 = zA[q], xA1 = zA[q+1];
        float4 xB0 = zB[q], xB1 = zB[q+1];
        a0 += w0.x*xA0.x + w0.y*xA0.y + w0.z*xA0.z + w0.w*xA0.w;
        b0 += w1.x*xA1.x + w1.y*xA1.y + w1.z*xA1.z + w1.w*xA1.w;
        a1 += w0.x*xB0.x + w0.y*xB0.y + w0.z*xB0.z + w0.w*xB0.w;
        b1 += w1.x*xB1.x + w1.y*xB1.y + w1.z*xB1.z + w1.w*xB1.w;
    }
    float s0 = a0 + b0, s1 = a1 + b1;
    s0 += __shfl_xor(s0, 1);       // combine half-dots within the pair
    s1 += __shfl_xor(s1, 1);
    *k0 = tanhf(s0 + ob)*rat0;
    *k1 = tanhf(s1 + ob)*rat1;
}

__global__ __launch_bounds__(256) void k_ode(
    const float* __restrict__ hpr, const float* __restrict__ hist_ts,
    const float* __restrict__ ode_w, const float* __restrict__ ode_b,
    const float* __restrict__ tnode_w, const float* __restrict__ tnode_b,
    float* __restrict__ out)
{
    __shared__ float zb[2][2*BPITCH];   // [buf][batch*BPITCH + slot], ~2.2 KB
    int tid = threadIdx.x;
    int j = tid >> 1, h = tid & 1;
    int b0 = blockIdx.x*2;

    float4 wr[16];
    const float4* wp = (const float4*)(ode_w + j*NF + h*64);
    #pragma unroll
    for (int i = 0; i < 16; ++i) wr[i] = wp[i];
    float twj = tnode_w[j], tbj = tnode_b[j], obj = ode_b[j];

    float z0, z1, t00, t01, rat0, rat1;
    {
        float t1a = hist_ts[(b0+0)*HL + (HL-1)];
        float t1b = hist_ts[(b0+1)*HL + (HL-1)];
        t00 = hist_ts[(b0+0)*HL + (HL-2)];
        t01 = hist_ts[(b0+1)*HL + (HL-2)];
        rat0 = t1a - t00; rat1 = t1b - t01;
        z0 = hpr[(b0+0)*NF + j];
        z1 = hpr[(b0+1)*NF + j];
    }

    // teA of step s+1 == teC of step s (s-grid exact in fp32) -> 4 cos/step
    float teA0 = cosf(t00*twj + tbj);
    float teA1 = cosf(t01*twj + tbj);
    #pragma unroll 1
    for (int stp = 0; stp < 8; ++stp) {
        float s0 = stp*0.125f;
        float teB0 = cosf(((s0 + 0.0625f)*rat0 + t00)*twj + tbj);
        float teB1 = cosf(((s0 + 0.0625f)*rat1 + t01)*twj + tbj);
        float teC0 = cosf(((s0 + 0.125f)*rat0 + t00)*twj + tbj);
        float teC1 = cosf(((s0 + 0.125f)*rat1 + t01)*twj + tbj);
        float k10, k11, k20, k21, k30, k31, k40, k41;
        ode_eval_pair(z0 + teA0,               z1 + teA1,               wr, obj, rat0, rat1, zb[0], j, h, &k10, &k11);
        ode_eval_pair(z0 + 0.0625f*k10 + teB0, z1 + 0.0625f*k11 + teB1, wr, obj, rat0, rat1, zb[1], j, h, &k20, &k21);
        ode_eval_pair(z0 + 0.0625f*k20 + teB0, z1 + 0.0625f*k21 + teB1, wr, obj, rat0, rat1, zb[0], j, h, &k30, &k31);
        ode_eval_pair(z0 + 0.125f*k30 + teC0,  z1 + 0.125f*k31 + teC1,  wr, obj, rat0, rat1, zb[1], j, h, &k40, &k41);
        z0 += (0.125f/6.f)*(k10 + 2.f*k20 + 2.f*k30 + k40);
        z1 += (0.125f/6.f)*(k11 + 2.f*k21 + 2.f*k31 + k41);
        teA0 = teC0; teA1 = teC1;
    }
    if (h == 0) {
        out[(b0+0)*NF + j] = z0;   // h_left
        out[(b0+1)*NF + j] = z1;
    }
}

// ---------------------------------------------------------------------------
extern "C" void kernel_launch(void* const* d_in, const int* in_sizes, int n_in,
                              void* d_out, int out_size, void* d_ws, size_t ws_size,
                              hipStream_t stream)
{
    (void)in_sizes; (void)n_in; (void)out_size; (void)ws_size;
    const int*   nids      = (const int*)d_in[0];
    const int*   hist_nids = (const int*)d_in[2];
    const int*   aids      = (const int*)d_in[3];
    const int*   eids      = (const int*)d_in[4];
    const float* hist_ts   = (const float*)d_in[5];
    const int*   dirs      = (const int*)d_in[6];
    const float* node_feat = (const float*)d_in[7];
    const float* edge_feat = (const float*)d_in[8];
    const float* anony_emb = (const float*)d_in[9];
    const float* time_w    = (const float*)d_in[10];
    const float* time_b    = (const float*)d_in[11];
    const float* in_proj_w = (const float*)d_in[12];
    const float* in_proj_b = (const float*)d_in[13];
    const float* out_proj_w= (const float*)d_in[14];
    const float* out_proj_b= (const float*)d_in[15];
    const float* outfn_w   = (const float*)d_in[16];
    const float* outfn_b   = (const float*)d_in[17];
    const float* attn_wq   = (const float*)d_in[18];
    const float* attn_wk   = (const float*)d_in[19];
    const float* attn_wv   = (const float*)d_in[20];
    const float* merge_w   = (const float*)d_in[21];
    const float* merge_b   = (const float*)d_in[22];
    const float* gru_w_ih  = (const float*)d_in[23];
    const float* gru_w_hh  = (const float*)d_in[24];
    const float* gru_b_ih  = (const float*)d_in[25];
    const float* gru_b_hh  = (const float*)d_in[26];
    const float* ode_w     = (const float*)d_in[27];
    const float* ode_b     = (const float*)d_in[28];
    const float* tnode_w   = (const float*)d_in[29];
    const float* tnode_b   = (const float*)d_in[30];
    float* out = (float*)d_out;

    float* ws    = (float*)d_ws;
    float* qc    = ws;                   // 640
    float* cc    = ws + 640;             // 2
    float* u     = ws + 768;             // 1280
    float* wbuf  = ws + 2048;            // 4096*1280
    float* lef   = wbuf + BSZ*2*DM;      // 4096*512
    float* qn    = lef + BSZ*DIN;        // 4096*128
    float* gi    = qn + BSZ*NF;          // 4096*384
    float* combT = gi + BSZ*3*NF;        // 640*128
    float* ZZ    = combT + DM*NF;        // 1280*128
    float* qb    = ZZ + 2*DM*NF;         // 128
    float* giT   = qb + NF;              // 512*384
    float* ghT   = giT + DIN*3*NF;       // 128*384
    // hpr aliases wbuf: wbuf's last reader (k_gemm_qn) precedes k_attn2 on
    // the same stream, so reuse is safe.
    float* hpr   = wbuf;                 // 4096*128

    // per-launch constant precomputes
    k_comb<<<DM, NF, 0, stream>>>(outfn_w, out_proj_w, combT);
    k_zz<<<2*DM, NF, 0, stream>>>(in_proj_w, combT, ZZ);
    k_qbias<<<1, NF, 0, stream>>>(outfn_b, out_proj_b, outfn_w, in_proj_b, combT, qb);
    k_transpose<<<960, 256, 0, stream>>>(gru_w_ih, gru_w_hh, giT, ghT);
    k_qc<<<5, 128, 0, stream>>>(time_b, in_proj_w, in_proj_b, qc);
    k_cc<<<1, 128, 0, stream>>>(qc, in_proj_b, cc);
    k_u<<<HL, 64, 0, stream>>>(qc, in_proj_w, u);

    // main pipeline
    k_attn1<<<BSZ, 256, 0, stream>>>(nids, hist_nids, aids, eids, hist_ts, dirs,
                                     node_feat, edge_feat, anony_emb,
                                     time_w, time_b, u, cc, wbuf, lef);
    k_gemm_qn<<<BSZ/8, 256, 0, stream>>>(wbuf, ZZ, qb, qn);
    k_gemm_gi<<<BSZ/8, 256, 0, stream>>>(lef, giT, gru_b_ih, gi);
    k_attn2<<<BSZ, 128, 0, stream>>>(nids, hist_nids, eids, hist_ts,
                                     node_feat, edge_feat, time_w, time_b,
                                     attn_wq, attn_wk, attn_wv, merge_w, merge_b,
                                     qn, gi, ghT, gru_b_hh, hpr, out);
    k_ode<<<BSZ/2, 256, 0, stream>>>(hpr, hist_ts, ode_w, ode_b,
                                     tnode_w, tnode_b, out);
}

// Round 3
// 952.265 us; speedup vs baseline: 1.1820x; 1.0567x over previous
//
#include <hip/hip_runtime.h>
#include <math.h>

// Problem constants (from reference)
#define BSZ 4096
#define HL  20
#define NF  128
#define DM  640      // 3*NF + EF + TF
#define DIN 512      // DM - TF
#define DH  320      // DM / NHEAD

static __device__ __forceinline__ float sigmoidf_(float x){ return 1.f/(1.f+expf(-x)); }
// bf16 truncate-with-round staging helpers (LDS footprint halving)
static __device__ __forceinline__ unsigned short f2b_(float v){
    return (unsigned short)((__float_as_uint(v) + 0x8000u) >> 16);
}
static __device__ __forceinline__ float b2f_(unsigned short u){
    return __uint_as_float(((unsigned int)u) << 16);
}

// ---------------------------------------------------------------------------
// T1: combT[jc*128+jq] = (outfn_w @ out_proj_w)[jq, jc]
// grid 640, block 128
__global__ void k_comb(const float* __restrict__ outfn_w,
                       const float* __restrict__ out_proj_w,
                       float* __restrict__ combT)
{
    int jc = blockIdx.x, jq = threadIdx.x;
    float acc = 0.f;
    for (int e = 0; e < DM; ++e)
        acc += outfn_w[jq*DM + e] * out_proj_w[e*DM + jc];
    combT[jc*NF + jq] = acc;
}

// T2: ZZ[ef*128+jq]
// grid 1280, block 128
__global__ void k_zz(const float* __restrict__ in_proj_w,
                     const float* __restrict__ combT,
                     float* __restrict__ ZZ)
{
    int ef = blockIdx.x;
    int h = ef / DM, e = ef - h*DM;
    int jq = threadIdx.x;
    const float* wv = in_proj_w + (2*DM + h*DH)*DM + e;   // + dd*DM
    const float* cb = combT + (h*DH)*NF + jq;             // + dd*NF
    float acc = 0.f;
    for (int dd = 0; dd < DH; ++dd)
        acc += wv[dd*DM] * cb[dd*NF];
    ZZ[ef*NF + jq] = acc;
}

// T3: qbias
// grid 1, block 128
__global__ void k_qbias(const float* __restrict__ outfn_b,
                        const float* __restrict__ out_proj_b,
                        const float* __restrict__ outfn_w,
                        const float* __restrict__ in_proj_b,
                        const float* __restrict__ combT,
                        float* __restrict__ qb)
{
    int jq = threadIdx.x;
    float acc = outfn_b[jq];
    for (int e = 0; e < DM; ++e)  acc += out_proj_b[e] * outfn_w[jq*DM + e];
    for (int jc = 0; jc < DM; ++jc) acc += in_proj_b[2*DM + jc] * combT[jc*NF + jq];
    qb[jq] = acc;
}

// T4: transposes
// grid 960, block 256
__global__ void k_transpose(const float* __restrict__ gih,
                            const float* __restrict__ ghh,
                            float* __restrict__ giT,
                            float* __restrict__ ghT)
{
    int i = blockIdx.x*blockDim.x + threadIdx.x;
    if (i < DIN*3*NF) {
        int d = i / (3*NF), j = i - d*(3*NF);
        giT[i] = gih[j*DIN + d];
    } else {
        int i2 = i - DIN*3*NF;
        int d = i2 / (3*NF), j = i2 - d*(3*NF);
        ghT[i2] = ghh[j*NF + d];
    }
}

// K2a: qc[j]
// grid 5, block 128
__global__ void k_qc(const float* __restrict__ time_b,
                     const float* __restrict__ in_proj_w,
                     const float* __restrict__ in_proj_b,
                     float* __restrict__ qcv)
{
    __shared__ float tsr[NF];
    int tid = threadIdx.x;
    tsr[tid] = cosf(time_b[tid]);
    __syncthreads();
    int j = blockIdx.x*128 + tid;
    const float* wr = in_proj_w + j*DM + DIN;
    float acc = in_proj_b[j];
    for (int d = 0; d < NF; ++d) acc += tsr[d]*wr[d];
    qcv[j] = acc;
}

// K2a2: cc[h]
// grid 1, block 128
__global__ void k_cc(const float* __restrict__ qcv,
                     const float* __restrict__ in_proj_b,
                     float* __restrict__ cc)
{
    int wave = threadIdx.x >> 6, lane = threadIdx.x & 63;
    float acc = 0.f;
    for (int j = lane; j < DH; j += 64)
        acc += qcv[wave*DH + j] * in_proj_b[DM + wave*DH + j];
    for (int off = 32; off > 0; off >>= 1) acc += __shfl_down(acc, off);
    if (lane == 0) cc[wave] = acc;
}

// K2b: u
// grid 20, block 64
__global__ void k_u(const float* __restrict__ qcv,
                    const float* __restrict__ in_proj_w,
                    float* __restrict__ u)
{
    int d = blockIdx.x*64 + threadIdx.x;
    int h = d / DM, dd = d - h*DM;
    const float* base = in_proj_w + (DM + h*DH)*DM + dd;
    const float* q = qcv + h*DH;
    float acc = 0.f;
    for (int j = 0; j < DH; ++j) acc += q[j]*base[j*DM];
    u[d] = acc;
}

// W1[d][dd] = sum_t attn_wq[d,t]*attn_wk[dd,t]   (folded query path)
// grid 384, block 128
__global__ void k_w1(const float* __restrict__ attn_wq,
                     const float* __restrict__ attn_wk,
                     float* __restrict__ W1)
{
    int dd = blockIdx.x, d = threadIdx.x;
    float acc = 0.f;
    for (int t = 0; t < NF; ++t)
        acc += attn_wq[d*NF + t] * attn_wk[dd*NF + t];
    W1[d*3*NF + dd] = acc;
}

// W2[d][j] = sum_q attn_wv[d,q]*merge_w[q,j]     (folded value path, top half)
// grid 384, block 128
__global__ void k_w2(const float* __restrict__ attn_wv,
                     const float* __restrict__ merge_w,
                     float* __restrict__ W2)
{
    int d = blockIdx.x, j = threadIdx.x;
    float acc = 0.f;
    for (int q = 0; q < NF; ++q)
        acc += attn_wv[d*NF + q] * merge_w[q*NF + j];
    W2[d*NF + j] = acc;
}

// ---------------------------------------------------------------------------
// K3: per-batch fused build + MHA attention (collapsed form), restructured:
// wave-per-row register gathering (40 outstanding loads/wave), score dot fused
// into the gather, bf16 LDS staging for the attention-weighted sum.
// grid 4096, block 256 (4 waves, 5 rows each)
__global__ __launch_bounds__(256) void k_attn1(
    const int* __restrict__ nids, const int* __restrict__ hist_nids,
    const int* __restrict__ aidsp, const int* __restrict__ eidsp,
    const float* __restrict__ hist_ts, const int* __restrict__ dirsp,
    const float* __restrict__ node_feat, const float* __restrict__ edge_feat,
    const float* __restrict__ anony_emb,
    const float* __restrict__ time_w, const float* __restrict__ time_b,
    const float* __restrict__ u, const float* __restrict__ cc,
    float* __restrict__ wbuf, float* __restrict__ lef)
{
    int b = blockIdx.x, tid = threadIdx.x;
    int wave = tid >> 6, lane = tid & 63;
    __shared__ unsigned short zh[HL][DM];   // 25.6 KB (bf16)
    __shared__ float ul[2*DM];              // 5 KB
    __shared__ float sc[2][HL];
    __shared__ float aw[2][HL];
    __shared__ int   shn[HL], sdir[HL], said[HL], seid[HL];
    __shared__ float sts[HL];

    if (tid < HL) {
        shn[tid]  = hist_nids[b*HL+tid];
        sdir[tid] = dirsp[b*HL+tid];
        said[tid] = aidsp[b*HL+tid];
        seid[tid] = eidsp[b*HL+tid];
        sts[tid]  = hist_ts[b*HL+tid];
    }
    for (int i = tid; i < 2*DM; i += 256) ul[i] = u[i];
    float twA = time_w[lane],    tbA = time_b[lane];
    float twB = time_w[64+lane], tbB = time_b[64+lane];
    __syncthreads();

    // preload u fragments for the fused score dot: c = lane + 64*s
    float ulr0[10], ulr1[10];
    #pragma unroll
    for (int s = 0; s < 10; ++s) {
        ulr0[s] = ul[s*64 + lane];
        ulr1[s] = ul[DM + s*64 + lane];
    }

    int rnid = nids[b];
    float tlast = sts[HL-1];

    // per-row indices (rows l = wave + 4*r)
    int srcv[5], dstv[5], aidv[5], eidv[5];
    float dtv[5];
    #pragma unroll
    for (int r = 0; r < 5; ++r) {
        int l = wave + 4*r;
        int hn = shn[l], dir = sdir[l];
        srcv[r] = dir ? rnid : hn;
        dstv[r] = dir ? hn : rnid;
        aidv[r] = said[l];
        eidv[r] = eidv[r] = seid[l];
        dtv[r]  = tlast - sts[l];
    }
    // issue all gathers (independent -> stay in flight together)
    float zr[5][10];
    #pragma unroll
    for (int r = 0; r < 5; ++r) {
        zr[r][0] = node_feat[srcv[r]*NF + lane];
        zr[r][1] = node_feat[srcv[r]*NF + 64 + lane];
        zr[r][2] = node_feat[dstv[r]*NF + lane];
        zr[r][3] = node_feat[dstv[r]*NF + 64 + lane];
        zr[r][4] = anony_emb[aidv[r]*NF + lane];
        zr[r][5] = anony_emb[aidv[r]*NF + 64 + lane];
        zr[r][6] = edge_feat[eidv[r]*NF + lane];
        zr[r][7] = edge_feat[eidv[r]*NF + 64 + lane];
        zr[r][8] = cosf(dtv[r]*twA + tbA);
        zr[r][9] = cosf(dtv[r]*twB + tbB);
    }
    float c0 = cc[0], c1 = cc[1];
    // process rows: lef write / zeroing, fused score dot, bf16 LDS store
    #pragma unroll
    for (int r = 0; r < 5; ++r) {
        int l = wave + 4*r;
        if (l == HL-1) {            // wave-uniform (wave 3, r 4 only)
            #pragma unroll
            for (int s = 0; s < 8; ++s) {
                lef[b*DIN + s*64 + lane] = zr[r][s];
                zr[r][s] = 0.f;
            }
        }
        float d0 = 0.f, d1 = 0.f;
        #pragma unroll
        for (int s = 0; s < 10; ++s) {
            float v = zr[r][s];
            d0 += ulr0[s]*v;
            d1 += ulr1[s]*v;
            zh[l][s*64 + lane] = f2b_(v);
        }
        for (int off = 32; off > 0; off >>= 1) {
            d0 += __shfl_down(d0, off);
            d1 += __shfl_down(d1, off);
        }
        if (lane == 0) {
            bool msk = (shn[l] == 0) && (l != HL-1);
            sc[0][l] = msk ? -1.0e9f : (d0 + c0)*0.05590169943749474f; // 1/sqrt(320)
            sc[1][l] = msk ? -1.0e9f : (d1 + c1)*0.05590169943749474f;
        }
    }
    __syncthreads();
    if (tid < 2) {
        float mx = -3.0e38f;
        for (int m = 0; m < HL; ++m) mx = fmaxf(mx, sc[tid][m]);
        float sum = 0.f;
        for (int m = 0; m < HL; ++m) { float e = expf(sc[tid][m]-mx); aw[tid][m] = e; sum += e; }
        float inv = 1.f/sum;
        for (int m = 0; m < HL; ++m) aw[tid][m] *= inv;
    }
    __syncthreads();
    #pragma unroll
    for (int i = tid; i < 2*DM; i += 256) {
        int h = i / DM, d = i - h*DM;
        float acc = 0.f;
        #pragma unroll
        for (int m = 0; m < HL; ++m) acc += aw[h][m]*b2f_(zh[m][d]);
        wbuf[b*2*DM + i] = acc;
    }
}

// ---------------------------------------------------------------------------
// Row-block GEMM: qn = wbuf @ ZZ + qbias
__global__ __launch_bounds__(256) void k_gemm_qn(const float* __restrict__ A,
                                                 const float* __restrict__ BT,
                                                 const float* __restrict__ bias,
                                                 float* __restrict__ C)
{
    constexpr int K = 2*DM;  // 1280
    __shared__ float As[8*K];   // 40 KB
    int r0 = blockIdx.x*8, tid = threadIdx.x;
    for (int i = tid; i < 8*K; i += 256) As[i] = A[r0*K + i];
    __syncthreads();
    int j = tid & (NF-1), rh = tid >> 7;
    const float* bp = BT + j;
    const float* ap = As + rh*4*K;
    float acc0=0.f, acc1=0.f, acc2=0.f, acc3=0.f;
    for (int d = 0; d < K; ++d) {
        float bv = bp[d*NF];
        acc0 += ap[d]*bv;
        acc1 += ap[K + d]*bv;
        acc2 += ap[2*K + d]*bv;
        acc3 += ap[3*K + d]*bv;
    }
    float bsv = bias[j];
    int rb = r0 + rh*4;
    C[(rb+0)*NF + j] = acc0 + bsv;
    C[(rb+1)*NF + j] = acc1 + bsv;
    C[(rb+2)*NF + j] = acc2 + bsv;
    C[(rb+3)*NF + j] = acc3 + bsv;
}

// Row-block GEMM: gi = lef @ giT + gru_b_ih
__global__ __launch_bounds__(256) void k_gemm_gi(const float* __restrict__ A,
                                                 const float* __restrict__ BT,
                                                 const float* __restrict__ bias,
                                                 float* __restrict__ C)
{
    constexpr int K = DIN;     // 512
    constexpr int N = 3*NF;    // 384
    __shared__ float As[8*K];  // 16 KB
    int r0 = blockIdx.x*8, tid = threadIdx.x;
    for (int i = tid; i < 8*K; i += 256) As[i] = A[r0*K + i];
    __syncthreads();
    int j0 = tid, j1 = tid + 256;
    bool has1 = (j1 < N);
    float a0[8] = {0,0,0,0,0,0,0,0};
    float a1[8] = {0,0,0,0,0,0,0,0};
    for (int d = 0; d < K; ++d) {
        float b0 = BT[d*N + j0];
        float b1 = 0.f;
        if (has1) b1 = BT[d*N + j1];
        #pragma unroll
        for (int r = 0; r < 8; ++r) {
            float av = As[r*K + d];
            a0[r] += av*b0;
            a1[r] += av*b1;
        }
    }
    float bs0 = bias[j0];
    for (int r = 0; r < 8; ++r) C[(r0+r)*N + j0] = a0[r] + bs0;
    if (has1) {
        float bs1 = bias[j1];
        for (int r = 0; r < 8; ++r) C[(r0+r)*N + j1] = a1[r] + bs1;
    }
}

// Row-block GEMM: p_all = qn @ W1 (no bias).  K=128, N=384.
__global__ __launch_bounds__(256) void k_gemm_p(const float* __restrict__ A,
                                                const float* __restrict__ BT,
                                                float* __restrict__ C)
{
    constexpr int K = NF;      // 128
    constexpr int N = 3*NF;    // 384
    __shared__ float As[8*K];  // 4 KB
    int r0 = blockIdx.x*8, tid = threadIdx.x;
    for (int i = tid; i < 8*K; i += 256) As[i] = A[r0*K + i];
    __syncthreads();
    int j0 = tid, j1 = tid + 256;
    bool has1 = (j1 < N);
    float a0[8] = {0,0,0,0,0,0,0,0};
    float a1[8] = {0,0,0,0,0,0,0,0};
    for (int d = 0; d < K; ++d) {
        float b0 = BT[d*N + j0];
        float b1 = 0.f;
        if (has1) b1 = BT[d*N + j1];
        #pragma unroll
        for (int r = 0; r < 8; ++r) {
            float av = As[r*K + d];
            a0[r] += av*b0;
            a1[r] += av*b1;
        }
    }
    for (int r = 0; r < 8; ++r) C[(r0+r)*N + j0] = a0[r];
    if (has1) {
        for (int r = 0; r < 8; ++r) C[(r0+r)*N + j1] = a1[r];
    }
}

// ---------------------------------------------------------------------------
// K4a: attention2 gather part only: score = p.nb, softmax, nbar = sum a*nb.
// grid 4096, block 256 (4 waves: wave-per-row score pass, thread-per-dim nbar)
__global__ __launch_bounds__(256) void k_attn2b(
    const int* __restrict__ hist_nids, const int* __restrict__ eidsp,
    const float* __restrict__ hist_ts,
    const float* __restrict__ node_feat, const float* __restrict__ edge_feat,
    const float* __restrict__ time_w, const float* __restrict__ time_b,
    const float* __restrict__ p_all,
    float* __restrict__ nbar_out)
{
    int b = blockIdx.x, tid = threadIdx.x;
    int wave = tid >> 6, lane = tid & 63;
    __shared__ float p[3*NF];
    __shared__ float scl[HL], al[HL];
    __shared__ int   shn[HL], seid[HL];
    __shared__ float sts[HL];

    if (tid < HL) {
        shn[tid]  = hist_nids[b*HL+tid];
        seid[tid] = eidsp[b*HL+tid];
        sts[tid]  = hist_ts[b*HL+tid];
    }
    for (int i = tid; i < 3*NF; i += 256) p[i] = p_all[b*3*NF + i];
    __syncthreads();

    float tlast = sts[HL-1];
    // sc[l] = (p . nb[l]) / sqrt(128), gathering nb[l] straight from global
    for (int l = wave; l < HL; l += 4) {
        int hn = shn[l], eid = seid[l];
        float dt = tlast - sts[l];
        float acc = 0.f;
        #pragma unroll
        for (int kk = 0; kk < 6; ++kk) {
            int d = lane + 64*kk;
            float v;
            if (d < NF)            v = node_feat[hn*NF + d];
            else if (d < 2*NF)     v = edge_feat[eid*NF + (d-NF)];
            else { int dd = d-2*NF; v = cosf(dt*time_w[dd] + time_b[dd]); }
            acc += p[d]*v;
        }
        for (int off = 32; off > 0; off >>= 1) acc += __shfl_down(acc, off);
        if (lane == 0) {
            bool msk = (hn == 0) && (l != HL-1);
            scl[l] = msk ? -1.0e9f : acc*0.08838834764831845f;  // 1/sqrt(128)
        }
    }
    __syncthreads();
    if (tid == 0) {
        float mx = -3.0e38f;
        for (int m = 0; m < HL; ++m) mx = fmaxf(mx, scl[m]);
        float sum = 0.f;
        for (int m = 0; m < HL; ++m) { float e = expf(scl[m]-mx); al[m] = e; sum += e; }
        float inv = 1.f/sum;
        for (int m = 0; m < HL; ++m) al[m] *= inv;
    }
    __syncthreads();
    // nbar = sum_l a[l]*nb[l]  (second gather pass, L2-warm), coalesced write
    for (int i = tid; i < 3*NF; i += 256) {
        float acc = 0.f;
        if (i < NF) {
            #pragma unroll
            for (int l = 0; l < HL; ++l) acc += al[l]*node_feat[shn[l]*NF + i];
        } else if (i < 2*NF) {
            int d = i - NF;
            #pragma unroll
            for (int l = 0; l < HL; ++l) acc += al[l]*edge_feat[seid[l]*NF + d];
        } else {
            int d = i - 2*NF;
            float twj = time_w[d], tbj = time_b[d];
            #pragma unroll
            for (int l = 0; l < HL; ++l) acc += al[l]*cosf((tlast - sts[l])*twj + tbj);
        }
        nbar_out[b*3*NF + i] = acc;
    }
}

// K4b: dense tail: hpl = tanh(nbar@W2 + nfn@merge_w_bot + b); gh = hpl@ghT;
// GRU -> hpr, out.  4 rows/block, 256 threads, grid BSZ/4 = 1024.
__global__ __launch_bounds__(256) void k_tail(
    const int* __restrict__ nids, const float* __restrict__ hist_ts,
    const float* __restrict__ node_feat,
    const float* __restrict__ nbar,      // [BSZ][384]
    const float* __restrict__ gi,        // [BSZ][384]
    const float* __restrict__ W2,        // [384][128]
    const float* __restrict__ merge_w,   // [256][128] (use rows 128..255)
    const float* __restrict__ merge_b,   // [128]
    const float* __restrict__ ghT,       // [128][384]
    const float* __restrict__ gru_b_hh,  // [384]
    float* __restrict__ hpr_out, float* __restrict__ out)
{
    constexpr int R = 4;
    __shared__ float S[R*3*NF];   // 6 KB nbar rows
    __shared__ float F[R*NF];     // 2 KB nfn rows
    __shared__ float Hp[R*NF];    // 2 KB hpl rows
    __shared__ int   nid4[R];
    int r0 = blockIdx.x*R, tid = threadIdx.x;
    if (tid < R) nid4[tid] = nids[r0+tid];
    __syncthreads();
    for (int i = tid; i < R*3*NF; i += 256) S[i] = nbar[r0*3*NF + i];
    for (int i = tid; i < R*NF; i += 256) {
        int r = i >> 7, d = i & 127;
        F[i] = node_feat[nid4[r]*NF + d];
    }
    __syncthreads();
    int j = tid & 127, rh = tid >> 7;     // rh in {0,1}: rows rh*2, rh*2+1
    // step 1: hpl
    float acc0 = merge_b[j], acc1 = acc0;
    const float* S0 = S + (rh*2+0)*3*NF;
    const float* S1 = S + (rh*2+1)*3*NF;
    for (int d = 0; d < 3*NF; ++d) {
        float w = W2[d*NF + j];
        acc0 += S0[d]*w;
        acc1 += S1[d]*w;
    }
    const float* F0 = F + (rh*2+0)*NF;
    const float* F1 = F + (rh*2+1)*NF;
    for (int d = 0; d < NF; ++d) {
        float w = merge_w[(NF+d)*NF + j];
        acc0 += F0[d]*w;
        acc1 += F1[d]*w;
    }
    Hp[(rh*2+0)*NF + j] = tanhf(acc0);
    Hp[(rh*2+1)*NF + j] = tanhf(acc1);
    __syncthreads();
    // step 2: gh + GRU
    #pragma unroll
    for (int q = 0; q < 2; ++q) {
        int r = rh*2 + q;
        const float* hp = Hp + r*NF;
        float g0 = gru_b_hh[j], g1 = gru_b_hh[NF+j], g2 = gru_b_hh[2*NF+j];
        for (int d = 0; d < NF; ++d) {
            float hv = hp[d];
            g0 += hv*ghT[d*3*NF + j];
            g1 += hv*ghT[d*3*NF + NF + j];
            g2 += hv*ghT[d*3*NF + 2*NF + j];
        }
        int rb = r0 + r;
        float gi0 = gi[rb*3*NF + j];
        float gi1 = gi[rb*3*NF + NF + j];
        float gi2 = gi[rb*3*NF + 2*NF + j];
        float hplv = hp[j];
        float r_ = sigmoidf_(gi0 + g0);
        float z_ = sigmoidf_(gi1 + g1);
        float n_ = tanhf(gi2 + r_*g2);
        float hpr = (1.f - z_)*n_ + z_*hplv;
        out[BSZ*NF + rb*NF + j] = hpr;    // h_right
        hpr_out[rb*NF + j] = hpr;         // for k_ode
    }
    if (tid < R) out[2*BSZ*NF + r0 + tid] = hist_ts[(r0+tid)*HL + (HL-1)];
}

// ---------------------------------------------------------------------------
// K5: batched RK4 ODE, half-row split.
// Thread (j = tid>>1, h = tid&1) holds W[j][h*64 .. h*64+63] (64 VGPRs) and
// computes a 64-wide partial dot; pair lanes (xor 1, intra-wave) combine via
// __shfl_xor. Double-buffered z-exchange -> ONE barrier per eval.
// z stored as [batch][h*68 + i] (4-float pad between halves) so the two
// broadcast addresses in each ds_read_b128 hit DISJOINT bank groups.
// Block 256 = 4 waves handles 2 batches; grid BSZ/2 = 2048.
// NOTE: no min-waves hint — __launch_bounds__(256,4) previously forced
// VGPR=64 and spilled wr[] to scratch (WRITE_SIZE 2->53 MB).
#define ZPITCH 68          // floats per half (64 data + 4 pad)
#define BPITCH (2*ZPITCH)  // floats per batch row (136)

static __device__ __forceinline__ void ode_eval_pair(
    float y0, float y1,            // this thread's element j of input vec, per batch
    const float4* __restrict__ wr, // 16 float4 = W[j][h*64 .. h*64+63]
    float ob, float rat0, float rat1,
    float* __restrict__ zrow,      // buffer base: [2][BPITCH] (batch-major)
    int j, int h, float* k0, float* k1)
{
    // pair threads hold identical y values; split the two stores across h
    int wslot = (j >> 6)*ZPITCH + (j & 63);
    if (h == 0) zrow[wslot]          = y0;
    else        zrow[BPITCH + wslot] = y1;
    __syncthreads();
    const float4* zA = (const float4*)(zrow + h*ZPITCH);            // batch 0, my half
    const float4* zB = (const float4*)(zrow + BPITCH + h*ZPITCH);   // batch 1, my half
    float a0 = 0.f, b0 = 0.f, a1 = 0.f, b1 = 0.f;                   // 4 acc chains (ILP)
    #pragma unroll
    for (int q = 0; q < 16; q += 2) {
        float4 w0 = wr[q],  w1 = wr[q+1];
        float4 xA0 = zA[q], xA1 = zA[q+1];
        float4 xB0 = zB[q], xB1 = zB[q+1];
        a0 += w0.x*xA0.x + w0.y*xA0.y + w0.z*xA0.z + w0.w*xA0.w;
        b0 += w1.x*xA1.x + w1.y*xA1.y + w1.z*xA1.z + w1.w*xA1.w;
        a1 += w0.x*xB0.x + w0.y*xB0.y + w0.z*xB0.z + w0.w*xB0.w;
        b1 += w1.x*xB1.x + w1.y*xB1.y + w1.z*xB1.z + w1.w*xB1.w;
    }
    float s0 = a0 + b0, s1 = a1 + b1;
    s0 += __shfl_xor(s0, 1);       // combine half-dots within the pair
    s1 += __shfl_xor(s1, 1);
    *k0 = tanhf(s0 + ob)*rat0;
    *k1 = tanhf(s1 + ob)*rat1;
}

__global__ __launch_bounds__(256) void k_ode(
    const float* __restrict__ hpr, const float* __restrict__ hist_ts,
    const float* __restrict__ ode_w, const float* __restrict__ ode_b,
    const float* __restrict__ tnode_w, const float* __restrict__ tnode_b,
    float* __restrict__ out)
{
    __shared__ float zb[2][2*BPITCH];   // [buf][batch*BPITCH + slot], ~2.2 KB
    int tid = threadIdx.x;
    int j = tid >> 1, h = tid & 1;
    int b0 = blockIdx.x*2;

    float4 wr[16];
    const float4* wp = (const float4*)(ode_w + j*NF + h*64);
    #pragma unroll
    for (int i = 0; i < 16; ++i) wr[i] = wp[i];
    float twj = tnode_w[j], tbj = tnode_b[j], obj = ode_b[j];

    float z0, z1, t00, t01, rat0, rat1;
    {
        float t1a = hist_ts[(b0+0)*HL + (HL-1)];
        float t1b = hist_ts[(b0+1)*HL + (HL-1)];
        t00 = hist_ts[(b0+0)*HL + (HL-2)];
        t01 = hist_ts[(b0+1)*HL + (HL-2)];
        rat0 = t1a - t00; rat1 = t1b - t01;
        z0 = hpr[(b0+0)*NF + j];
        z1 = hpr[(b0+1)*NF + j];
    }

    // teA of step s+1 == teC of step s (s-grid exact in fp32) -> 4 cos/step
    float teA0 = cosf(t00*twj + tbj);
    float teA1 = cosf(t01*twj + tbj);
    #pragma unroll 1
    for (int stp = 0; stp < 8; ++stp) {
        float s0 = stp*0.125f;
        float teB0 = cosf(((s0 + 0.0625f)*rat0 + t00)*twj + tbj);
        float teB1 = cosf(((s0 + 0.0625f)*rat1 + t01)*twj + tbj);
        float teC0 = cosf(((s0 + 0.125f)*rat0 + t00)*twj + tbj);
        float teC1 = cosf(((s0 + 0.125f)*rat1 + t01)*twj + tbj);
        float k10, k11, k20, k21, k30, k31, k40, k41;
        ode_eval_pair(z0 + teA0,               z1 + teA1,               wr, obj, rat0, rat1, zb[0], j, h, &k10, &k11);
        ode_eval_pair(z0 + 0.0625f*k10 + teB0, z1 + 0.0625f*k11 + teB1, wr, obj, rat0, rat1, zb[1], j, h, &k20, &k21);
        ode_eval_pair(z0 + 0.0625f*k20 + teB0, z1 + 0.0625f*k21 + teB1, wr, obj, rat0, rat1, zb[0], j, h, &k30, &k31);
        ode_eval_pair(z0 + 0.125f*k30 + teC0,  z1 + 0.125f*k31 + teC1,  wr, obj, rat0, rat1, zb[1], j, h, &k40, &k41);
        z0 += (0.125f/6.f)*(k10 + 2.f*k20 + 2.f*k30 + k40);
        z1 += (0.125f/6.f)*(k11 + 2.f*k21 + 2.f*k31 + k41);
        teA0 = teC0; teA1 = teC1;
    }
    if (h == 0) {
        out[(b0+0)*NF + j] = z0;   // h_left
        out[(b0+1)*NF + j] = z1;
    }
}

// ---------------------------------------------------------------------------
extern "C" void kernel_launch(void* const* d_in, const int* in_sizes, int n_in,
                              void* d_out, int out_size, void* d_ws, size_t ws_size,
                              hipStream_t stream)
{
    (void)in_sizes; (void)n_in; (void)out_size; (void)ws_size;
    const int*   nids      = (const int*)d_in[0];
    const int*   hist_nids = (const int*)d_in[2];
    const int*   aids      = (const int*)d_in[3];
    const int*   eids      = (const int*)d_in[4];
    const float* hist_ts   = (const float*)d_in[5];
    const int*   dirs      = (const int*)d_in[6];
    const float* node_feat = (const float*)d_in[7];
    const float* edge_feat = (const float*)d_in[8];
    const float* anony_emb = (const float*)d_in[9];
    const float* time_w    = (const float*)d_in[10];
    const float* time_b    = (const float*)d_in[11];
    const float* in_proj_w = (const float*)d_in[12];
    const float* in_proj_b = (const float*)d_in[13];
    const float* out_proj_w= (const float*)d_in[14];
    const float* out_proj_b= (const float*)d_in[15];
    const float* outfn_w   = (const float*)d_in[16];
    const float* outfn_b   = (const float*)d_in[17];
    const float* attn_wq   = (const float*)d_in[18];
    const float* attn_wk   = (const float*)d_in[19];
    const float* attn_wv   = (const float*)d_in[20];
    const float* merge_w   = (const float*)d_in[21];
    const float* merge_b   = (const float*)d_in[22];
    const float* gru_w_ih  = (const float*)d_in[23];
    const float* gru_w_hh  = (const float*)d_in[24];
    const float* gru_b_ih  = (const float*)d_in[25];
    const float* gru_b_hh  = (const float*)d_in[26];
    const float* ode_w     = (const float*)d_in[27];
    const float* ode_b     = (const float*)d_in[28];
    const float* tnode_w   = (const float*)d_in[29];
    const float* tnode_b   = (const float*)d_in[30];
    float* out = (float*)d_out;

    float* ws    = (float*)d_ws;
    float* qc    = ws;                   // 640
    float* cc    = ws + 640;             // 2
    float* u     = ws + 768;             // 1280
    float* wbuf  = ws + 2048;            // 4096*1280
    float* lef   = wbuf + BSZ*2*DM;      // 4096*512
    float* qn    = lef + BSZ*DIN;        // 4096*128
    float* gi    = qn + BSZ*NF;          // 4096*384
    float* combT = gi + BSZ*3*NF;        // 640*128
    float* ZZ    = combT + DM*NF;        // 1280*128
    float* qb    = ZZ + 2*DM*NF;         // 128
    float* giT   = qb + NF;              // 512*384
    float* ghT   = giT + DIN*3*NF;       // 128*384
    float* W1    = ghT + NF*3*NF;        // 128*384
    float* W2    = W1 + NF*3*NF;         // 384*128
    // Aliases (stream-ordered reuse):
    //   p_all aliases lef  (lef's last reader k_gemm_gi precedes k_gemm_p)
    //   nbar  aliases wbuf (wbuf's last reader k_gemm_qn precedes k_attn2b)
    //   hpr   at wbuf+BSZ*3*NF, disjoint from nbar
    float* p_all = lef;                  // 4096*384 (<= 4096*512)
    float* nbar  = wbuf;                 // 4096*384
    float* hpr   = wbuf + BSZ*3*NF;      // 4096*128

    // per-launch constant precomputes
    k_comb<<<DM, NF, 0, stream>>>(outfn_w, out_proj_w, combT);
    k_zz<<<2*DM, NF, 0, stream>>>(in_proj_w, combT, ZZ);
    k_qbias<<<1, NF, 0, stream>>>(outfn_b, out_proj_b, outfn_w, in_proj_b, combT, qb);
    k_transpose<<<960, 256, 0, stream>>>(gru_w_ih, gru_w_hh, giT, ghT);
    k_qc<<<5, 128, 0, stream>>>(time_b, in_proj_w, in_proj_b, qc);
    k_cc<<<1, 128, 0, stream>>>(qc, in_proj_b, cc);
    k_u<<<HL, 64, 0, stream>>>(qc, in_proj_w, u);
    k_w1<<<3*NF, NF, 0, stream>>>(attn_wq, attn_wk, W1);
    k_w2<<<3*NF, NF, 0, stream>>>(attn_wv, merge_w, W2);

    // main pipeline
    k_attn1<<<BSZ, 256, 0, stream>>>(nids, hist_nids, aids, eids, hist_ts, dirs,
                                     node_feat, edge_feat, anony_emb,
                                     time_w, time_b, u, cc, wbuf, lef);
    k_gemm_qn<<<BSZ/8, 256, 0, stream>>>(wbuf, ZZ, qb, qn);
    k_gemm_gi<<<BSZ/8, 256, 0, stream>>>(lef, giT, gru_b_ih, gi);
    k_gemm_p<<<BSZ/8, 256, 0, stream>>>(qn, W1, p_all);
    k_attn2b<<<BSZ, 256, 0, stream>>>(hist_nids, eids, hist_ts,
                                      node_feat, edge_feat, time_w, time_b,
                                      p_all, nbar);
    k_tail<<<BSZ/4, 256, 0, stream>>>(nids, hist_ts, node_feat, nbar, gi,
                                      W2, merge_w, merge_b, ghT, gru_b_hh,
                                      hpr, out);
    k_ode<<<BSZ/2, 256, 0, stream>>>(hpr, hist_ts, ode_w, ode_b,
                                     tnode_w, tnode_b, out);
}